// Round 3
// baseline (268.128 us; speedup 1.0000x reference)
//
#include <hip/hip_runtime.h>
#include <hip/hip_bf16.h>
#include <stdint.h>

// DeformableBlock: fused [offset-conv (MFMA) + meta + deformable conv (MFMA GEMM)]
// -> GroupNorm+ReLU.  B=4, CIN=COUT=256, H=W=64, 3x3, GN groups=32.
// Round 12: barrier-free phase B. R10/R11 evidence: all pipes <25% busy, traffic
// reduction didn't help, block-wide barriers every chunk are the limiter.
//  - Phase B gathers directly in MFMA B-frag layout (lane&15=px, lane>>4=oct):
//    blend in registers, NO LDS for B, NO barriers (2 barriers total in kernel).
//  - Each wave = private M=64 x N=32 x K=2304 GEMM, fully desynced.
//  - 512 blocks x 256 thr (4-wave R9 phase A), XCD swizzle, fused GN partials.

typedef unsigned short u16;
typedef __bf16 bf16x8 __attribute__((ext_vector_type(8)));
typedef float f32x4_t __attribute__((ext_vector_type(4)));

#define HW 4096

__device__ __forceinline__ uint32_t f32_to_bf16_rne(float f) {
  uint32_t u = __builtin_bit_cast(uint32_t, f);
  return (u + 0x7FFFu + ((u >> 16) & 1u)) >> 16;
}
__device__ __forceinline__ float bf_lo(uint32_t u) {
  return __builtin_bit_cast(float, u << 16);
}
__device__ __forceinline__ float bf_hi(uint32_t u) {
  return __builtin_bit_cast(float, u & 0xFFFF0000u);
}
__device__ __forceinline__ uint32_t blend2(uint32_t a, uint32_t b, uint32_t c,
                                           uint32_t d, float4 mw) {
  float lo = mw.x * bf_lo(a) + mw.y * bf_lo(b) + mw.z * bf_lo(c) + mw.w * bf_lo(d);
  float hi = mw.x * bf_hi(a) + mw.y * bf_hi(b) + mw.z * bf_hi(c) + mw.w * bf_hi(d);
  return f32_to_bf16_rne(lo) | (f32_to_bf16_rne(hi) << 16);
}

// ---------------- Kernel PRE: transpose + weight prep + zero part (merged) ----------------
__global__ __launch_bounds__(256) void k_pre(const float* __restrict__ x,
                                             const float* __restrict__ wsrc,
                                             const float* __restrict__ ow,
                                             u16* __restrict__ xt,
                                             u16* __restrict__ warr,
                                             u16* __restrict__ owm,
                                             float* __restrict__ part) {
  __shared__ float tile[32][33];
  int bid = blockIdx.x;
  int tid = threadIdx.x;
  if (bid < 4096) {
    int bx = bid & 127, by = (bid >> 7) & 7, bz = bid >> 10;
    int c0 = by * 32, p0 = bx * 32;
    int tx = tid & 31, ty = tid >> 5;  // 32 x 8
#pragma unroll
    for (int j = 0; j < 32; j += 8)
      tile[ty + j][tx] = x[(bz * 256 + c0 + ty + j) * HW + p0 + tx];
    __syncthreads();
    int cp = tid & 15;
    int pr = tid >> 4;
#pragma unroll
    for (int j = 0; j < 2; j++) {
      int p = pr + j * 16;
      uint32_t lo = f32_to_bf16_rne(tile[cp * 2][p]);
      uint32_t hi = f32_to_bf16_rne(tile[cp * 2 + 1][p]);
      *(uint32_t*)&xt[(bz * HW + p0 + p) * 256 + c0 + cp * 2] = lo | (hi << 16);
    }
  } else if (bid < 6400) {
    int e = (bid - 4096) * 256 + tid;  // < 589824
    int kk = e & 7, m = (e >> 3) & 255, g = (e >> 11) & 7, kc = e >> 14;
    int cin = (kc & 3) * 64 + g * 8 + kk;
    int tap = kc >> 2;
    warr[e] = (u16)f32_to_bf16_rne(wsrc[m * 2304 + cin * 9 + tap]);
  } else if (bid < 6688) {
    int e = (bid - 6400) * 256 + tid;  // < 73728
    int kk = e & 7, m = (e >> 3) & 31, g = (e >> 8) & 7, kc = e >> 11;
    int cin = (kc & 3) * 64 + g * 8 + kk;
    int tap = kc >> 2;
    float v = (m < 18) ? ow[m * 2304 + cin * 9 + tap] : 0.f;
    owm[e] = (u16)f32_to_bf16_rne(v);
  } else {
    part[tid] = 0.f;  // 4 b * 32 groups * {s,ss} = 256 floats
  }
}

// ---------------- Kernel C: FUSED offset-conv + meta + barrier-free deformable GEMM ----------------
// Block = (b, 32-px tile), 512 blocks x 256 threads (4 waves, M=64/wave).
// Phase A: offset conv M=32,N=32,K=2304 (4 waves split taps, wave-private LDS
//          staging, zero barriers).  Meta -> LDS.  [2 barriers total]
// Phase B: per-wave private GEMM M=64, N=32, K=2304. Gathers land directly in
//          B-frag layout (lane&15=px, lane>>4=k-octet); blend in registers;
//          no LDS, no barriers. A-frags from warr (L2-hot via XCD swizzle).
// Epilogue: out stores + fused GN partial sums (shfl reduce + atomics).
__global__ __launch_bounds__(256, 2) void k_conv(
    const u16* __restrict__ xt, const u16* __restrict__ warr,
    const u16* __restrict__ owm, const float* __restrict__ ob,
    float* __restrict__ out, float* __restrict__ part) {
  __shared__ char smem[27136];
  u16* stage = (u16*)smem;                   // phase A: [w4][2112 u16] (16896 B)
  float* off_part = (float*)(smem + 16896);  // phase A: [w4][px32][20]  (10240 B)
  int4* ci_s = (int4*)smem;                  // meta/B:  [288]           (4608 B)
  float4* mw_s = (float4*)(smem + 4608);     // meta/B:  [288]           (4608 B)

  int tid = threadIdx.x;
  int lane = tid & 63;
  int wm = tid >> 6;  // 0..3
  // XCD-aware bijective swizzle (512 blocks, 8 XCDs): each XCD gets 64
  // consecutive work-ids = 32 consecutive rows of ONE image (~2.4 MB working set).
  int wk = (blockIdx.x & 7) * 64 + (blockIdx.x >> 3);
  int b = wk >> 7;
  int pt = wk & 127;
  int p0 = pt * 32;
  int yrow = p0 >> 6, xbase = p0 & 63;

  // ---- Phase A: offset conv; wave w handles taps w, w+4, w+8 ----
  {
    u16* st = stage + wm * 2112;
    int q = lane & 15, pq = lane >> 4;
    f32x4_t a2[2][2] = {};
#pragma unroll 1
    for (int tap = wm; tap < 9; tap += 4) {
      int ky = tap / 3, kx = tap % 3;
      int yy = yrow + ky - 1;
      bool vy = (yy >= 0) && (yy < 64);
#pragma unroll
      for (int cc = 0; cc < 4; cc++) {
        int kc = tap * 4 + cc;
#pragma unroll
        for (int i = 0; i < 8; i++) {
          int px = i * 4 + pq;
          int xx2 = xbase + px + kx - 1;
          uint2 v = make_uint2(0u, 0u);
          if (vy && xx2 >= 0 && xx2 < 64)
            v = *(const uint2*)&xt[(b * HW + yy * 64 + xx2) * 256 + cc * 64 + q * 4];
          *(uint2*)&st[(q >> 1) * 264 + px * 8 + (q & 1) * 4] = v;
        }
#pragma unroll
        for (int ks = 0; ks < 2; ks++) {
          int g = ks * 4 + pq;
          const u16* ab = owm + kc * 2048 + g * 256;
#pragma unroll
          for (int s = 0; s < 2; s++) {
            bf16x8 bfr = *(bf16x8*)&st[g * 264 + (s * 16 + q) * 8];
#pragma unroll
            for (int im = 0; im < 2; im++) {
              bf16x8 af = *(const bf16x8*)&ab[(im * 16 + q) * 8];
              a2[s][im] = __builtin_amdgcn_mfma_f32_16x16x32_bf16(af, bfr, a2[s][im], 0, 0, 0);
            }
          }
        }
      }
    }
    // D: col = q (px within sub), row = pq*4+r (+im*16) = oc
#pragma unroll
    for (int s = 0; s < 2; s++)
#pragma unroll
      for (int im = 0; im < 2; im++)
#pragma unroll
        for (int r = 0; r < 4; r++) {
          int oc = im * 16 + pq * 4 + r;
          if (oc < 18) off_part[(wm * 32 + s * 16 + q) * 20 + oc] = a2[s][im][r];
        }
  }
  __syncthreads();
  // ---- meta: 288 = 9 taps x 32 px; results to LDS (aliases dead stage) ----
  for (int it = tid; it < 288; it += 256) {
    int tap = it >> 5;
    int px = it & 31;
    float dy = ob[2 * tap], dx = ob[2 * tap + 1];
#pragma unroll
    for (int wv = 0; wv < 4; wv++) {
      dy += off_part[(wv * 32 + px) * 20 + 2 * tap];
      dx += off_part[(wv * 32 + px) * 20 + 2 * tap + 1];
    }
    int ky = tap / 3, kx = tap % 3;
    int p = p0 + px;
    int yq = p >> 6, xq = p & 63;
    float py = (float)(yq - 1 + ky) + dy;
    float pxx = (float)(xq - 1 + kx) + dx;
    float y0f = floorf(py), x0f = floorf(pxx);
    float ty = py - y0f, tx = pxx - x0f;
    int y0 = (int)y0f, x0 = (int)x0f;
    int y1 = y0 + 1, x1 = x0 + 1;
    float wy0 = 1.f - ty, wy1 = ty, wx0 = 1.f - tx, wx1 = tx;
    bool vy0 = (y0 >= 0) && (y0 < 64), vy1 = (y1 >= 0) && (y1 < 64);
    bool vx0 = (x0 >= 0) && (x0 < 64), vx1 = (x1 >= 0) && (x1 < 64);
    int cy0 = min(max(y0, 0), 63), cy1 = min(max(y1, 0), 63);
    int cx0 = min(max(x0, 0), 63), cx1 = min(max(x1, 0), 63);
    int base = b * HW;
    int4 ci;
    ci.x = (base + cy0 * 64 + cx0) * 256;
    ci.y = (base + cy0 * 64 + cx1) * 256;
    ci.z = (base + cy1 * 64 + cx0) * 256;
    ci.w = (base + cy1 * 64 + cx1) * 256;
    float4 mw;
    mw.x = wy0 * wx0 * ((vy0 && vx0) ? 1.f : 0.f);
    mw.y = wy0 * wx1 * ((vy0 && vx1) ? 1.f : 0.f);
    mw.z = wy1 * wx0 * ((vy1 && vx0) ? 1.f : 0.f);
    mw.w = wy1 * wx1 * ((vy1 && vx1) ? 1.f : 0.f);
    ci_s[it] = ci;
    mw_s[it] = mw;
  }
  __syncthreads();

  // ---- Phase B: wave-private GEMM M=64, N=32, K=2304 (no LDS, no barriers) ----
  {
    int col = lane & 15;  // px within subtile AND m-row within 16-group
    int pq = lane >> 4;   // k-octet within 32-ch k-step
    f32x4_t acc[2][4] = {};  // [sub][im]

#pragma unroll 1
    for (int tap = 0; tap < 9; tap++) {
      int4 ci0 = ci_s[tap * 32 + col];       // broadcast across pq (free)
      int4 ci1 = ci_s[tap * 32 + 16 + col];
      float4 mw0 = mw_s[tap * 32 + col];
      float4 mw1 = mw_s[tap * 32 + 16 + col];
#pragma unroll 2
      for (int cc = 0; cc < 4; cc++) {
        int kc = tap * 4 + cc;
        const u16* wbase = warr + kc * 16384 + pq * 2048 + (wm * 64 + col) * 8;
#pragma unroll
        for (int h = 0; h < 2; h++) {
          int e = cc * 64 + h * 32 + pq * 8;  // channel slice matches A's gg=h*4+pq
          uint4 a0 = *(const uint4*)&xt[ci0.x + e];
          uint4 a1 = *(const uint4*)&xt[ci0.y + e];
          uint4 a2v = *(const uint4*)&xt[ci0.z + e];
          uint4 a3 = *(const uint4*)&xt[ci0.w + e];
          uint4 b0 = *(const uint4*)&xt[ci1.x + e];
          uint4 b1 = *(const uint4*)&xt[ci1.y + e];
          uint4 b2 = *(const uint4*)&xt[ci1.z + e];
          uint4 b3 = *(const uint4*)&xt[ci1.w + e];
          uint4 f0, f1;
          f0.x = blend2(a0.x, a1.x, a2v.x, a3.x, mw0);
          f0.y = blend2(a0.y, a1.y, a2v.y, a3.y, mw0);
          f0.z = blend2(a0.z, a1.z, a2v.z, a3.z, mw0);
          f0.w = blend2(a0.w, a1.w, a2v.w, a3.w, mw0);
          f1.x = blend2(b0.x, b1.x, b2.x, b3.x, mw1);
          f1.y = blend2(b0.y, b1.y, b2.y, b3.y, mw1);
          f1.z = blend2(b0.z, b1.z, b2.z, b3.z, mw1);
          f1.w = blend2(b0.w, b1.w, b2.w, b3.w, mw1);
          bf16x8 bf0 = *(bf16x8*)&f0;
          bf16x8 bf1 = *(bf16x8*)&f1;
          const u16* ab = wbase + h * 4 * 2048;  // gg = h*4 + pq
#pragma unroll
          for (int im = 0; im < 4; im++) {
            bf16x8 af = *(const bf16x8*)&ab[im * 128];
            acc[0][im] = __builtin_amdgcn_mfma_f32_16x16x32_bf16(af, bf0, acc[0][im], 0, 0, 0);
            acc[1][im] = __builtin_amdgcn_mfma_f32_16x16x32_bf16(af, bf1, acc[1][im], 0, 0, 0);
          }
        }
      }
    }

    // epilogue: D col=px-in-sub, row=pq*4+r -> NCHW; fused GN partial sums
#pragma unroll
    for (int im = 0; im < 4; im++) {
      float s = 0.f, ss = 0.f;
#pragma unroll
      for (int sb = 0; sb < 2; sb++) {
        int n = p0 + sb * 16 + col;
#pragma unroll
        for (int r = 0; r < 4; r++) {
          int m = wm * 64 + im * 16 + pq * 4 + r;
          float v = acc[sb][im][r];
          out[(b * 256 + m) * HW + n] = v;
          s += v;
          ss += v * v;
        }
      }
      // this thread's 8 values share one GN group; groups split at lane 32
#pragma unroll
      for (int msk = 1; msk <= 16; msk <<= 1) {
        s += __shfl_xor(s, msk);
        ss += __shfl_xor(ss, msk);
      }
      if ((lane & 31) == 0) {
        int grp = wm * 8 + im * 2 + (lane >> 5);
        float* pp = part + (b * 32 + grp) * 2;
        atomicAdd(pp, s);
        atomicAdd(pp + 1, ss);
      }
    }
  }
}

// ---------------- Kernel N: finalize stats + normalize + ReLU in place ----------------
__global__ __launch_bounds__(256) void k_gn_apply(float* __restrict__ out,
                                                  const float2* __restrict__ part,
                                                  const float* __restrict__ gamma,
                                                  const float* __restrict__ beta) {
  __shared__ float sga, sbe;
  int gid = blockIdx.x * 256 + threadIdx.x;  // float4 index, < 1048576
  int c = (gid >> 10) & 255;
  int bb = gid >> 18;
  if (threadIdx.x == 0) {
    float2 p = part[bb * 32 + (c >> 3)];
    float mu = p.x / 32768.f;
    float var = p.y / 32768.f - mu * mu;
    float rs = rsqrtf(var + 1e-5f);
    float ga = gamma[c] * rs;
    sga = ga;
    sbe = beta[c] - mu * ga;
  }
  __syncthreads();
  float ga = sga, be = sbe;
  float4 v = ((const float4*)out)[gid];
  v.x = fmaxf(v.x * ga + be, 0.f);
  v.y = fmaxf(v.y * ga + be, 0.f);
  v.z = fmaxf(v.z * ga + be, 0.f);
  v.w = fmaxf(v.w * ga + be, 0.f);
  ((float4*)out)[gid] = v;
}

extern "C" void kernel_launch(void* const* d_in, const int* in_sizes, int n_in,
                              void* d_out, int out_size, void* d_ws, size_t ws_size,
                              hipStream_t stream) {
  const float* x = (const float*)d_in[0];
  const float* offset_w = (const float*)d_in[1];
  const float* offset_b = (const float*)d_in[2];
  const float* deform_w = (const float*)d_in[3];
  const float* gn_gamma = (const float*)d_in[4];
  const float* gn_beta = (const float*)d_in[5];
  float* out = (float*)d_out;
  char* ws = (char*)d_ws;

  u16* xt = (u16*)ws;                      //  8,388,608 B (bf16 NHWC)
  u16* warr = (u16*)(ws + 8388608);        //  1,179,648 B
  u16* owm = (u16*)(ws + 9568256);         //    147,456 B
  float* part = (float*)(ws + 9715712);    //      1,024 B (4b x 32g x {s,ss})

  k_pre<<<dim3(6689), dim3(256), 0, stream>>>(x, deform_w, offset_w, xt, warr, owm, part);
  k_conv<<<dim3(512), dim3(256), 0, stream>>>(xt, warr, owm, offset_b, out, part);
  k_gn_apply<<<dim3(4096), dim3(256), 0, stream>>>(out, (const float2*)part, gn_gamma, gn_beta);
}

// Round 4
// 184.058 us; speedup vs baseline: 1.4568x; 1.4568x over previous
//
#include <hip/hip_runtime.h>
#include <hip/hip_bf16.h>
#include <stdint.h>

// DeformableBlock: B=4, CIN=COUT=256, H=W=64, 3x3, GN groups=32.
// Round 13: decouple B-production from GEMM consumption.
//  R9-R12 evidence: the fused gather/blend->LDS->MFMA chain is insensitive to
//  occupancy, traffic, and barrier count -- the scattered B-production sits on
//  the GEMM critical path in every fusion. So: materialize blended B to global
//  (75.5 MB bf16) in k_off (coalesced gathers, barrier-free after meta), then
//  run k_mm as a canonical GEMM (clean coalesced staging, reg-prefetch, 16KB LDS).
//  ws guard: falls back to the proven R10 fused k_conv if ws_size < 85.3 MB.

typedef unsigned short u16;
typedef __bf16 bf16x8 __attribute__((ext_vector_type(8)));
typedef float f32x4_t __attribute__((ext_vector_type(4)));

#define HW 4096

__device__ __forceinline__ uint32_t f32_to_bf16_rne(float f) {
  uint32_t u = __builtin_bit_cast(uint32_t, f);
  return (u + 0x7FFFu + ((u >> 16) & 1u)) >> 16;
}
__device__ __forceinline__ float bf_lo(uint32_t u) {
  return __builtin_bit_cast(float, u << 16);
}
__device__ __forceinline__ float bf_hi(uint32_t u) {
  return __builtin_bit_cast(float, u & 0xFFFF0000u);
}
__device__ __forceinline__ uint32_t blend2(uint32_t a, uint32_t b, uint32_t c,
                                           uint32_t d, float4 mw) {
  float lo = mw.x * bf_lo(a) + mw.y * bf_lo(b) + mw.z * bf_lo(c) + mw.w * bf_lo(d);
  float hi = mw.x * bf_hi(a) + mw.y * bf_hi(b) + mw.z * bf_hi(c) + mw.w * bf_hi(d);
  return f32_to_bf16_rne(lo) | (f32_to_bf16_rne(hi) << 16);
}

// ---------------- Kernel PRE: transpose + weight prep + zero part (merged) ----------------
__global__ __launch_bounds__(256) void k_pre(const float* __restrict__ x,
                                             const float* __restrict__ wsrc,
                                             const float* __restrict__ ow,
                                             u16* __restrict__ xt,
                                             u16* __restrict__ warr,
                                             u16* __restrict__ owm,
                                             float* __restrict__ part) {
  __shared__ float tile[32][33];
  int bid = blockIdx.x;
  int tid = threadIdx.x;
  if (bid < 4096) {
    int bx = bid & 127, by = (bid >> 7) & 7, bz = bid >> 10;
    int c0 = by * 32, p0 = bx * 32;
    int tx = tid & 31, ty = tid >> 5;  // 32 x 8
#pragma unroll
    for (int j = 0; j < 32; j += 8)
      tile[ty + j][tx] = x[(bz * 256 + c0 + ty + j) * HW + p0 + tx];
    __syncthreads();
    int cp = tid & 15;
    int pr = tid >> 4;
#pragma unroll
    for (int j = 0; j < 2; j++) {
      int p = pr + j * 16;
      uint32_t lo = f32_to_bf16_rne(tile[cp * 2][p]);
      uint32_t hi = f32_to_bf16_rne(tile[cp * 2 + 1][p]);
      *(uint32_t*)&xt[(bz * HW + p0 + p) * 256 + c0 + cp * 2] = lo | (hi << 16);
    }
  } else if (bid < 6400) {
    int e = (bid - 4096) * 256 + tid;  // < 589824
    int kk = e & 7, m = (e >> 3) & 255, g = (e >> 11) & 7, kc = e >> 14;
    int cin = (kc & 3) * 64 + g * 8 + kk;
    int tap = kc >> 2;
    warr[e] = (u16)f32_to_bf16_rne(wsrc[m * 2304 + cin * 9 + tap]);
  } else if (bid < 6688) {
    int e = (bid - 6400) * 256 + tid;  // < 73728
    int kk = e & 7, m = (e >> 3) & 31, g = (e >> 8) & 7, kc = e >> 11;
    int cin = (kc & 3) * 64 + g * 8 + kk;
    int tap = kc >> 2;
    float v = (m < 18) ? ow[m * 2304 + cin * 9 + tap] : 0.f;
    owm[e] = (u16)f32_to_bf16_rne(v);
  } else {
    part[tid] = 0.f;  // 4 b * 32 groups * {s,ss} = 256 floats
  }
}

// ---------------- Kernel OFF: offset-conv + meta + blend -> Bmat global ----------------
// Block = (b, 32-px tile), 512 blocks x 256 thr (4 waves).
// Phase A: offset conv M=32,N=32,K=2304 (waves split taps, wave-private staging).
// Meta -> LDS. Blend: 36 iters x 256 thr; lanes oct-fastest -> coalesced 512B
// corner reads; writes Bmat[wk][ko 288][px 32][kk 8] bf16 (16B per thread).
__global__ __launch_bounds__(256, 2) void k_off(
    const u16* __restrict__ xt, const u16* __restrict__ owm,
    const float* __restrict__ ob, u16* __restrict__ bmat) {
  __shared__ char smem[27136];
  u16* stage = (u16*)smem;                   // phase A: [w4][2112 u16] (16896 B)
  float* off_part = (float*)(smem + 16896);  // phase A: [w4][px32][20]  (10240 B)
  int4* ci_s = (int4*)smem;                  // meta:    [288]           (4608 B)
  float4* mw_s = (float4*)(smem + 4608);     // meta:    [288]           (4608 B)

  int tid = threadIdx.x;
  int lane = tid & 63;
  int wm = tid >> 6;  // 0..3
  int wk = (blockIdx.x & 7) * 64 + (blockIdx.x >> 3);  // XCD swizzle
  int b = wk >> 7;
  int pt = wk & 127;
  int p0 = pt * 32;
  int yrow = p0 >> 6, xbase = p0 & 63;

  // ---- Phase A: offset conv; wave w handles taps w, w+4, w+8 ----
  {
    u16* st = stage + wm * 2112;
    int q = lane & 15, pq = lane >> 4;
    f32x4_t a2[2][2] = {};
#pragma unroll 1
    for (int tap = wm; tap < 9; tap += 4) {
      int ky = tap / 3, kx = tap % 3;
      int yy = yrow + ky - 1;
      bool vy = (yy >= 0) && (yy < 64);
#pragma unroll
      for (int cc = 0; cc < 4; cc++) {
        int kc = tap * 4 + cc;
#pragma unroll
        for (int i = 0; i < 8; i++) {
          int px = i * 4 + pq;
          int xx2 = xbase + px + kx - 1;
          uint2 v = make_uint2(0u, 0u);
          if (vy && xx2 >= 0 && xx2 < 64)
            v = *(const uint2*)&xt[(b * HW + yy * 64 + xx2) * 256 + cc * 64 + q * 4];
          *(uint2*)&st[(q >> 1) * 264 + px * 8 + (q & 1) * 4] = v;
        }
#pragma unroll
        for (int ks = 0; ks < 2; ks++) {
          int g = ks * 4 + pq;
          const u16* ab = owm + kc * 2048 + g * 256;
#pragma unroll
          for (int s = 0; s < 2; s++) {
            bf16x8 bfr = *(bf16x8*)&st[g * 264 + (s * 16 + q) * 8];
#pragma unroll
            for (int im = 0; im < 2; im++) {
              bf16x8 af = *(const bf16x8*)&ab[(im * 16 + q) * 8];
              a2[s][im] = __builtin_amdgcn_mfma_f32_16x16x32_bf16(af, bfr, a2[s][im], 0, 0, 0);
            }
          }
        }
      }
    }
#pragma unroll
    for (int s = 0; s < 2; s++)
#pragma unroll
      for (int im = 0; im < 2; im++)
#pragma unroll
        for (int r = 0; r < 4; r++) {
          int oc = im * 16 + pq * 4 + r;
          if (oc < 18) off_part[(wm * 32 + s * 16 + q) * 20 + oc] = a2[s][im][r];
        }
  }
  __syncthreads();
  // ---- meta: 288 = 9 taps x 32 px (aliases dead stage) ----
  for (int it = tid; it < 288; it += 256) {
    int tap = it >> 5;
    int px = it & 31;
    float dy = ob[2 * tap], dx = ob[2 * tap + 1];
#pragma unroll
    for (int wv = 0; wv < 4; wv++) {
      dy += off_part[(wv * 32 + px) * 20 + 2 * tap];
      dx += off_part[(wv * 32 + px) * 20 + 2 * tap + 1];
    }
    int ky = tap / 3, kx = tap % 3;
    int p = p0 + px;
    int yq = p >> 6, xq = p & 63;
    float py = (float)(yq - 1 + ky) + dy;
    float pxx = (float)(xq - 1 + kx) + dx;
    float y0f = floorf(py), x0f = floorf(pxx);
    float ty = py - y0f, tx = pxx - x0f;
    int y0 = (int)y0f, x0 = (int)x0f;
    int y1 = y0 + 1, x1 = x0 + 1;
    float wy0 = 1.f - ty, wy1 = ty, wx0 = 1.f - tx, wx1 = tx;
    bool vy0 = (y0 >= 0) && (y0 < 64), vy1 = (y1 >= 0) && (y1 < 64);
    bool vx0 = (x0 >= 0) && (x0 < 64), vx1 = (x1 >= 0) && (x1 < 64);
    int cy0 = min(max(y0, 0), 63), cy1 = min(max(y1, 0), 63);
    int cx0 = min(max(x0, 0), 63), cx1 = min(max(x1, 0), 63);
    int base = b * HW;
    int4 ci;
    ci.x = (base + cy0 * 64 + cx0) * 256;
    ci.y = (base + cy0 * 64 + cx1) * 256;
    ci.z = (base + cy1 * 64 + cx0) * 256;
    ci.w = (base + cy1 * 64 + cx1) * 256;
    float4 mw;
    mw.x = wy0 * wx0 * ((vy0 && vx0) ? 1.f : 0.f);
    mw.y = wy0 * wx1 * ((vy0 && vx1) ? 1.f : 0.f);
    mw.z = wy1 * wx0 * ((vy1 && vx0) ? 1.f : 0.f);
    mw.w = wy1 * wx1 * ((vy1 && vx1) ? 1.f : 0.f);
    ci_s[it] = ci;
    mw_s[it] = mw;
  }
  __syncthreads();

  // ---- blend: 9216 items = 9 taps x 32 oct x 32 px; barrier-free ----
  u16* bt = bmat + (size_t)wk * 73728;
#pragma unroll 1
  for (int it = 0; it < 36; it++) {
    int idx = it * 256 + tid;
    int oct = idx & 31;          // channel octet (oct*8 .. +7)
    int px = (idx >> 5) & 31;
    int tap = idx >> 10;
    int4 ci = ci_s[tap * 32 + px];
    float4 mw = mw_s[tap * 32 + px];
    int e = oct * 8;
    uint4 c0 = *(const uint4*)&xt[ci.x + e];
    uint4 c1 = *(const uint4*)&xt[ci.y + e];
    uint4 c2 = *(const uint4*)&xt[ci.z + e];
    uint4 c3 = *(const uint4*)&xt[ci.w + e];
    uint4 u;
    u.x = blend2(c0.x, c1.x, c2.x, c3.x, mw);
    u.y = blend2(c0.y, c1.y, c2.y, c3.y, mw);
    u.z = blend2(c0.z, c1.z, c2.z, c3.z, mw);
    u.w = blend2(c0.w, c1.w, c2.w, c3.w, mw);
    *(uint4*)&bt[((tap * 32 + oct) * 32 + px) * 8] = u;
  }
}

// ---------------- Kernel MM: canonical GEMM M=256, N=32/tile, K=2304 ----------------
// Block = (b, 32-px tile), 512 blocks x 512 thr (8 waves, M=32/wave, 2 N-subtiles).
// Staging: one coalesced uint4/thread/chunk from Bmat, reg-prefetched one chunk
// ahead; 18 chunks x 1 barrier; LDS 16 KB. Fused GN partial sums in epilogue.
__global__ __launch_bounds__(512, 8) void k_mm(
    const u16* __restrict__ warr, const u16* __restrict__ bmat,
    float* __restrict__ out, float* __restrict__ part) {
  __shared__ u16 b_s[8192];  // [2 buf][ko 16][px 32][kk 8]

  int tid = threadIdx.x;
  int lane = tid & 63;
  int wm = tid >> 6;  // 0..7
  int wk = (blockIdx.x & 7) * 64 + (blockIdx.x >> 3);  // same swizzle as k_off
  int b = wk >> 7;
  int pt = wk & 127;
  int p0 = pt * 32;
  int col = lane & 15;
  int pq = lane >> 4;
  const u16* bt = bmat + (size_t)wk * 73728;

  f32x4_t acc[2][2] = {};  // [sub][im]
  uint4 cur = *(const uint4*)&bt[tid * 8];  // chunk 0

#pragma unroll 1
  for (int d = 0; d < 18; d++) {
    u16* bb = b_s + (d & 1) * 4096;
    *(uint4*)&bb[tid * 8] = cur;
    __syncthreads();
    if (d < 17) cur = *(const uint4*)&bt[(d + 1) * 4096 + tid * 8];
    int tap = d >> 1, half = d & 1;
#pragma unroll
    for (int ks = 0; ks < 4; ks++) {
      int ro = ks * 4 + pq;
      bf16x8 b0 = *(bf16x8*)&bb[(ro * 32 + col) * 8];
      bf16x8 b1 = *(bf16x8*)&bb[(ro * 32 + 16 + col) * 8];
      int kc = tap * 4 + half * 2 + (ks >> 1);
      int gg = (ks & 1) * 4 + pq;
      const u16* ab = warr + kc * 16384 + gg * 2048 + (wm * 32 + col) * 8;
#pragma unroll
      for (int im = 0; im < 2; im++) {
        bf16x8 af = *(const bf16x8*)&ab[im * 128];
        acc[0][im] = __builtin_amdgcn_mfma_f32_16x16x32_bf16(af, b0, acc[0][im], 0, 0, 0);
        acc[1][im] = __builtin_amdgcn_mfma_f32_16x16x32_bf16(af, b1, acc[1][im], 0, 0, 0);
      }
    }
    // no trailing barrier: next d writes the other buffer (2-deep rotation safe)
  }

  // epilogue: D col=px-in-sub, row=pq*4+r -> NCHW; fused GN partial sums
#pragma unroll
  for (int im = 0; im < 2; im++) {
    float s = 0.f, ss = 0.f;
#pragma unroll
    for (int sb = 0; sb < 2; sb++) {
      int n = p0 + sb * 16 + col;
#pragma unroll
      for (int r = 0; r < 4; r++) {
        int m = wm * 32 + im * 16 + pq * 4 + r;
        float v = acc[sb][im][r];
        out[(b * 256 + m) * HW + n] = v;
        s += v;
        ss += v * v;
      }
    }
#pragma unroll
    for (int msk = 1; msk <= 16; msk <<= 1) {
      s += __shfl_xor(s, msk);
      ss += __shfl_xor(ss, msk);
    }
    if ((lane & 31) == 0) {
      int grp = wm * 4 + im * 2 + (lane >> 5);
      float* pp = part + (b * 32 + grp) * 2;
      atomicAdd(pp, s);
      atomicAdd(pp + 1, ss);
    }
  }
}

// ---------------- Fallback (R10): fused offset-conv + meta + GEMM + GN partials ----------------
__global__ __launch_bounds__(512, 4) void k_conv(
    const u16* __restrict__ xt, const u16* __restrict__ warr,
    const u16* __restrict__ owm, const float* __restrict__ ob,
    float* __restrict__ out, float* __restrict__ part) {
  __shared__ char smem[54272];
  u16* stage = (u16*)smem;
  float* off_part = (float*)(smem + 33792);
  int4* ci_s = (int4*)smem;
  float4* mw_s = (float4*)(smem + 4608);
  u16* b_s = (u16*)(smem + 9216);

  int tid = threadIdx.x;
  int lane = tid & 63;
  int wm = tid >> 6;
  int b = blockIdx.x >> 7;
  int pt = blockIdx.x & 127;
  int p0 = pt * 32;
  int yrow = p0 >> 6, xbase = p0 & 63;

  {
    u16* st = stage + wm * 2112;
    int q = lane & 15, pq = lane >> 4;
    int oct = lane & 7, pxs = lane >> 3;
    f32x4_t a2[2][2] = {};
#pragma unroll 1
    for (int kc = wm; kc < 36; kc += 8) {
      int tap = kc >> 2, cc = kc & 3;
      int ky = tap / 3, kx = tap % 3;
      int yy = yrow + ky - 1;
      bool vy = (yy >= 0) && (yy < 64);
#pragma unroll
      for (int i = 0; i < 4; i++) {
        int px = i * 8 + pxs;
        int xx2 = xbase + px + kx - 1;
        uint4 v = make_uint4(0u, 0u, 0u, 0u);
        if (vy && xx2 >= 0 && xx2 < 64)
          v = *(const uint4*)&xt[(b * HW + yy * 64 + xx2) * 256 + cc * 64 + oct * 8];
        *(uint4*)&st[oct * 264 + px * 8] = v;
      }
#pragma unroll
      for (int ks = 0; ks < 2; ks++) {
        int g = ks * 4 + pq;
        const u16* ab = owm + kc * 2048 + g * 256;
#pragma unroll
        for (int s = 0; s < 2; s++) {
          bf16x8 bfr = *(bf16x8*)&st[g * 264 + (s * 16 + q) * 8];
#pragma unroll
          for (int im = 0; im < 2; im++) {
            bf16x8 af = *(const bf16x8*)&ab[(im * 16 + q) * 8];
            a2[s][im] = __builtin_amdgcn_mfma_f32_16x16x32_bf16(af, bfr, a2[s][im], 0, 0, 0);
          }
        }
      }
    }
#pragma unroll
    for (int s = 0; s < 2; s++)
#pragma unroll
      for (int im = 0; im < 2; im++)
#pragma unroll
        for (int r = 0; r < 4; r++) {
          int oc = im * 16 + pq * 4 + r;
          if (oc < 18) off_part[(wm * 32 + s * 16 + q) * 20 + oc] = a2[s][im][r];
        }
  }
  __syncthreads();
  for (int it = tid; it < 288; it += 512) {
    int tap = it >> 5;
    int px = it & 31;
    float dy = ob[2 * tap], dx = ob[2 * tap + 1];
#pragma unroll
    for (int wv = 0; wv < 8; wv++) {
      dy += off_part[(wv * 32 + px) * 20 + 2 * tap];
      dx += off_part[(wv * 32 + px) * 20 + 2 * tap + 1];
    }
    int ky = tap / 3, kx = tap % 3;
    int p = p0 + px;
    int yq = p >> 6, xq = p & 63;
    float py = (float)(yq - 1 + ky) + dy;
    float pxx = (float)(xq - 1 + kx) + dx;
    float y0f = floorf(py), x0f = floorf(pxx);
    float ty = py - y0f, tx = pxx - x0f;
    int y0 = (int)y0f, x0 = (int)x0f;
    int y1 = y0 + 1, x1 = x0 + 1;
    float wy0 = 1.f - ty, wy1 = ty, wx0 = 1.f - tx, wx1 = tx;
    bool vy0 = (y0 >= 0) && (y0 < 64), vy1 = (y1 >= 0) && (y1 < 64);
    bool vx0 = (x0 >= 0) && (x0 < 64), vx1 = (x1 >= 0) && (x1 < 64);
    int cy0 = min(max(y0, 0), 63), cy1 = min(max(y1, 0), 63);
    int cx0 = min(max(x0, 0), 63), cx1 = min(max(x1, 0), 63);
    int base = b * HW;
    int4 ci;
    ci.x = (base + cy0 * 64 + cx0) * 256;
    ci.y = (base + cy0 * 64 + cx1) * 256;
    ci.z = (base + cy1 * 64 + cx0) * 256;
    ci.w = (base + cy1 * 64 + cx1) * 256;
    float4 mw;
    mw.x = wy0 * wx0 * ((vy0 && vx0) ? 1.f : 0.f);
    mw.y = wy0 * wx1 * ((vy0 && vx1) ? 1.f : 0.f);
    mw.z = wy1 * wx0 * ((vy1 && vx0) ? 1.f : 0.f);
    mw.w = wy1 * wx1 * ((vy1 && vx1) ? 1.f : 0.f);
    ci_s[it] = ci;
    mw_s[it] = mw;
  }
  __syncthreads();

  {
    int oct8 = tid & 15;
    int pxg = tid >> 4;
    int sub = pxg >> 4;
    int pxw = pxg & 15;
    int col = lane & 15;
    int pq = lane >> 4;
    f32x4_t acc[2][2] = {};

    int4 ci = ci_s[pxg];
    float4 mw = mw_s[pxg];
    int e = oct8 * 8;
    uint4 c0 = *(const uint4*)&xt[ci.x + e];
    uint4 c1 = *(const uint4*)&xt[ci.y + e];
    uint4 c2 = *(const uint4*)&xt[ci.z + e];
    uint4 c3 = *(const uint4*)&xt[ci.w + e];

#pragma unroll 1
    for (int dccg = 0; dccg < 18; dccg++) {
      u16* bb = b_s + (dccg & 1) * 4352;
      uint4 u;
      u.x = blend2(c0.x, c1.x, c2.x, c3.x, mw);
      u.y = blend2(c0.y, c1.y, c2.y, c3.y, mw);
      u.z = blend2(c0.z, c1.z, c2.z, c3.z, mw);
      u.w = blend2(c0.w, c1.w, c2.w, c3.w, mw);
      *(uint4*)&bb[sub * 2176 + oct8 * 136 + pxw * 8] = u;
      __syncthreads();
      if (dccg < 17) {
        int nx = dccg + 1;
        int tapn = nx >> 1;
        int en = (nx & 1) * 128 + oct8 * 8;
        int4 cin = ci_s[tapn * 32 + pxg];
        float4 mwn = mw_s[tapn * 32 + pxg];
        c0 = *(const uint4*)&xt[cin.x + en];
        c1 = *(const uint4*)&xt[cin.y + en];
        c2 = *(const uint4*)&xt[cin.z + en];
        c3 = *(const uint4*)&xt[cin.w + en];
        mw = mwn;
      }
      int tap = dccg >> 1, dcc = dccg & 1;
#pragma unroll
      for (int ks = 0; ks < 4; ks++) {
        int ro = ks * 4 + pq;
        bf16x8 b0 = *(bf16x8*)&bb[ro * 136 + col * 8];
        bf16x8 b1 = *(bf16x8*)&bb[2176 + ro * 136 + col * 8];
        int kc = tap * 4 + dcc * 2 + (ks >> 1);
        int g = (ks & 1) * 4 + pq;
        const u16* ab = warr + kc * 16384 + g * 2048 + (wm * 32 + col) * 8;
#pragma unroll
        for (int im = 0; im < 2; im++) {
          bf16x8 af = *(const bf16x8*)&ab[im * 128];
          acc[0][im] = __builtin_amdgcn_mfma_f32_16x16x32_bf16(af, b0, acc[0][im], 0, 0, 0);
          acc[1][im] = __builtin_amdgcn_mfma_f32_16x16x32_bf16(af, b1, acc[1][im], 0, 0, 0);
        }
      }
    }

#pragma unroll
    for (int im = 0; im < 2; im++) {
      float s = 0.f, ss = 0.f;
#pragma unroll
      for (int sb = 0; sb < 2; sb++) {
        int n = p0 + sb * 16 + col;
#pragma unroll
        for (int r = 0; r < 4; r++) {
          int m = wm * 32 + im * 16 + pq * 4 + r;
          float v = acc[sb][im][r];
          out[(b * 256 + m) * HW + n] = v;
          s += v;
          ss += v * v;
        }
      }
#pragma unroll
      for (int msk = 1; msk <= 16; msk <<= 1) {
        s += __shfl_xor(s, msk);
        ss += __shfl_xor(ss, msk);
      }
      if ((lane & 31) == 0) {
        int g = wm * 4 + im * 2 + (lane >> 5);
        float* pp = part + (b * 32 + g) * 2;
        atomicAdd(pp, s);
        atomicAdd(pp + 1, ss);
      }
    }
  }
}

// ---------------- Kernel N: finalize stats + normalize + ReLU in place ----------------
__global__ __launch_bounds__(256) void k_gn_apply(float* __restrict__ out,
                                                  const float2* __restrict__ part,
                                                  const float* __restrict__ gamma,
                                                  const float* __restrict__ beta) {
  __shared__ float sga, sbe;
  int gid = blockIdx.x * 256 + threadIdx.x;  // float4 index, < 1048576
  int c = (gid >> 10) & 255;
  int bb = gid >> 18;
  if (threadIdx.x == 0) {
    float2 p = part[bb * 32 + (c >> 3)];
    float mu = p.x / 32768.f;
    float var = p.y / 32768.f - mu * mu;
    float rs = rsqrtf(var + 1e-5f);
    float ga = gamma[c] * rs;
    sga = ga;
    sbe = beta[c] - mu * ga;
  }
  __syncthreads();
  float ga = sga, be = sbe;
  float4 v = ((const float4*)out)[gid];
  v.x = fmaxf(v.x * ga + be, 0.f);
  v.y = fmaxf(v.y * ga + be, 0.f);
  v.z = fmaxf(v.z * ga + be, 0.f);
  v.w = fmaxf(v.w * ga + be, 0.f);
  ((float4*)out)[gid] = v;
}

extern "C" void kernel_launch(void* const* d_in, const int* in_sizes, int n_in,
                              void* d_out, int out_size, void* d_ws, size_t ws_size,
                              hipStream_t stream) {
  const float* x = (const float*)d_in[0];
  const float* offset_w = (const float*)d_in[1];
  const float* offset_b = (const float*)d_in[2];
  const float* deform_w = (const float*)d_in[3];
  const float* gn_gamma = (const float*)d_in[4];
  const float* gn_beta = (const float*)d_in[5];
  float* out = (float*)d_out;
  char* ws = (char*)d_ws;

  u16* xt = (u16*)ws;                      //  8,388,608 B (bf16 NHWC)
  u16* warr = (u16*)(ws + 8388608);        //  1,179,648 B
  u16* owm = (u16*)(ws + 9568256);         //    147,456 B
  float* part = (float*)(ws + 9715712);    //      1,024 B
  u16* bmat = (u16*)(ws + 9716736);        // 75,497,472 B (blended B, bf16)

  k_pre<<<dim3(6689), dim3(256), 0, stream>>>(x, deform_w, offset_w, xt, warr, owm, part);
  if (ws_size >= 85214208ull) {
    k_off<<<dim3(512), dim3(256), 0, stream>>>(xt, owm, offset_b, bmat);
    k_mm<<<dim3(512), dim3(512), 0, stream>>>(warr, bmat, out, part);
  } else {
    k_conv<<<dim3(512), dim3(512), 0, stream>>>(xt, warr, owm, offset_b, out, part);
  }
  k_gn_apply<<<dim3(4096), dim3(256), 0, stream>>>(out, (const float2*)part, gn_gamma, gn_beta);
}

// Round 5
// 157.682 us; speedup vs baseline: 1.7004x; 1.1673x over previous
//
#include <hip/hip_runtime.h>
#include <hip/hip_bf16.h>
#include <stdint.h>

// DeformableBlock: fused [offset-conv (MFMA) + meta + deformable conv (MFMA GEMM)]
// -> GroupNorm+ReLU.  B=4, CIN=COUT=256, H=W=64, 3x3, GN groups=32.
// Round 14: revert R13 split (bmat round-trip lost); back to R10 fused k_conv with:
//  - pair-wise 2-register-set gather prefetch: consume window 0.5 -> 1.5 chunks
//  - XCD-aware bijective swizzle (proven FETCH 30->9.6 MB in R11/R13)
//  - s_setprio(1) around MFMA (2 blocks/CU at different phases -> T5 applies)
//  - k_gn_apply: barrier-free stats (all threads compute; loads broadcast)

typedef unsigned short u16;
typedef __bf16 bf16x8 __attribute__((ext_vector_type(8)));
typedef float f32x4_t __attribute__((ext_vector_type(4)));

#define HW 4096

__device__ __forceinline__ uint32_t f32_to_bf16_rne(float f) {
  uint32_t u = __builtin_bit_cast(uint32_t, f);
  return (u + 0x7FFFu + ((u >> 16) & 1u)) >> 16;
}
__device__ __forceinline__ float bf_lo(uint32_t u) {
  return __builtin_bit_cast(float, u << 16);
}
__device__ __forceinline__ float bf_hi(uint32_t u) {
  return __builtin_bit_cast(float, u & 0xFFFF0000u);
}
__device__ __forceinline__ uint32_t blend2(uint32_t a, uint32_t b, uint32_t c,
                                           uint32_t d, float4 mw) {
  float lo = mw.x * bf_lo(a) + mw.y * bf_lo(b) + mw.z * bf_lo(c) + mw.w * bf_lo(d);
  float hi = mw.x * bf_hi(a) + mw.y * bf_hi(b) + mw.z * bf_hi(c) + mw.w * bf_hi(d);
  return f32_to_bf16_rne(lo) | (f32_to_bf16_rne(hi) << 16);
}

// ---------------- Kernel PRE: transpose + weight prep + zero part (merged) ----------------
__global__ __launch_bounds__(256) void k_pre(const float* __restrict__ x,
                                             const float* __restrict__ wsrc,
                                             const float* __restrict__ ow,
                                             u16* __restrict__ xt,
                                             u16* __restrict__ warr,
                                             u16* __restrict__ owm,
                                             float* __restrict__ part) {
  __shared__ float tile[32][33];
  int bid = blockIdx.x;
  int tid = threadIdx.x;
  if (bid < 4096) {
    int bx = bid & 127, by = (bid >> 7) & 7, bz = bid >> 10;
    int c0 = by * 32, p0 = bx * 32;
    int tx = tid & 31, ty = tid >> 5;  // 32 x 8
#pragma unroll
    for (int j = 0; j < 32; j += 8)
      tile[ty + j][tx] = x[(bz * 256 + c0 + ty + j) * HW + p0 + tx];
    __syncthreads();
    int cp = tid & 15;
    int pr = tid >> 4;
#pragma unroll
    for (int j = 0; j < 2; j++) {
      int p = pr + j * 16;
      uint32_t lo = f32_to_bf16_rne(tile[cp * 2][p]);
      uint32_t hi = f32_to_bf16_rne(tile[cp * 2 + 1][p]);
      *(uint32_t*)&xt[(bz * HW + p0 + p) * 256 + c0 + cp * 2] = lo | (hi << 16);
    }
  } else if (bid < 6400) {
    int e = (bid - 4096) * 256 + tid;  // < 589824
    int kk = e & 7, m = (e >> 3) & 255, g = (e >> 11) & 7, kc = e >> 14;
    int cin = (kc & 3) * 64 + g * 8 + kk;
    int tap = kc >> 2;
    warr[e] = (u16)f32_to_bf16_rne(wsrc[m * 2304 + cin * 9 + tap]);
  } else if (bid < 6688) {
    int e = (bid - 6400) * 256 + tid;  // < 73728
    int kk = e & 7, m = (e >> 3) & 31, g = (e >> 8) & 7, kc = e >> 11;
    int cin = (kc & 3) * 64 + g * 8 + kk;
    int tap = kc >> 2;
    float v = (m < 18) ? ow[m * 2304 + cin * 9 + tap] : 0.f;
    owm[e] = (u16)f32_to_bf16_rne(v);
  } else {
    part[tid] = 0.f;  // 4 b * 32 groups * {s,ss} = 256 floats
  }
}

// ---------------- Kernel C: FUSED offset-conv + meta + deformable GEMM + GN partials ----------------
// Block = (b, 32-px tile), 512 blocks x 512 threads (8 waves, M=32/wave).
// Phase A: offset conv M=32,N=32,K=2304; 8 waves split the 36 kc-chunks
// (wave-private LDS staging, zero barriers). Meta -> LDS.
// Phase B: deformable GEMM M=256,N=32, 18 chunks of 128 ch; 2 gather register
// sets (even/odd chunk of same tap) reloaded right after their blend -> each
// load has a ~1.5-chunk consume window; LDS B double-buffered; 1 barrier/chunk.
__global__ __launch_bounds__(512, 4) void k_conv(
    const u16* __restrict__ xt, const u16* __restrict__ warr,
    const u16* __restrict__ owm, const float* __restrict__ ob,
    float* __restrict__ out, float* __restrict__ part) {
  __shared__ char smem[54272];
  u16* stage = (u16*)smem;                   // phase A: [w8][2112 u16] (33792 B)
  float* off_part = (float*)(smem + 33792);  // phase A: [w8][px32][20]  (20480 B)
  int4* ci_s = (int4*)smem;                  // meta/B:  [288]           (4608 B)
  float4* mw_s = (float4*)(smem + 4608);     // meta/B:  [288]           (4608 B)
  u16* b_s = (u16*)(smem + 9216);            // phase B: [2buf][2sub][16oct][136 u16] (17408 B)

  int tid = threadIdx.x;
  int lane = tid & 63;
  int wm = tid >> 6;  // 0..7
  // XCD-aware bijective swizzle (512 blocks, 8 XCDs): each XCD gets 64
  // consecutive work-ids = 64 consecutive 32-px tiles (L2 working set ~2.4 MB).
  int wk = (blockIdx.x & 7) * 64 + (blockIdx.x >> 3);
  int b = wk >> 7;
  int pt = wk & 127;
  int p0 = pt * 32;
  int yrow = p0 >> 6, xbase = p0 & 63;

  // ---- Phase A: offset conv; wave w handles kc-chunks w, w+8, w+16, ... ----
  {
    u16* st = stage + wm * 2112;
    int q = lane & 15, pq = lane >> 4;
    int oct = lane & 7, pxs = lane >> 3;  // staging map (uint4 loads)
    f32x4_t a2[2][2] = {};
#pragma unroll 1
    for (int kc = wm; kc < 36; kc += 8) {
      int tap = kc >> 2, cc = kc & 3;
      int ky = tap / 3, kx = tap % 3;
      int yy = yrow + ky - 1;
      bool vy = (yy >= 0) && (yy < 64);
#pragma unroll
      for (int i = 0; i < 4; i++) {
        int px = i * 8 + pxs;
        int xx2 = xbase + px + kx - 1;
        uint4 v = make_uint4(0u, 0u, 0u, 0u);
        if (vy && xx2 >= 0 && xx2 < 64)
          v = *(const uint4*)&xt[(b * HW + yy * 64 + xx2) * 256 + cc * 64 + oct * 8];
        *(uint4*)&st[oct * 264 + px * 8] = v;
      }
#pragma unroll
      for (int ks = 0; ks < 2; ks++) {
        int g = ks * 4 + pq;
        const u16* ab = owm + kc * 2048 + g * 256;
#pragma unroll
        for (int s = 0; s < 2; s++) {
          bf16x8 bfr = *(bf16x8*)&st[g * 264 + (s * 16 + q) * 8];
#pragma unroll
          for (int im = 0; im < 2; im++) {
            bf16x8 af = *(const bf16x8*)&ab[(im * 16 + q) * 8];
            a2[s][im] = __builtin_amdgcn_mfma_f32_16x16x32_bf16(af, bfr, a2[s][im], 0, 0, 0);
          }
        }
      }
    }
#pragma unroll
    for (int s = 0; s < 2; s++)
#pragma unroll
      for (int im = 0; im < 2; im++)
#pragma unroll
        for (int r = 0; r < 4; r++) {
          int oc = im * 16 + pq * 4 + r;
          if (oc < 18) off_part[(wm * 32 + s * 16 + q) * 20 + oc] = a2[s][im][r];
        }
  }
  __syncthreads();
  // ---- meta: 288 = 9 taps x 32 px; results to LDS (aliases dead stage) ----
  for (int it = tid; it < 288; it += 512) {
    int tap = it >> 5;
    int px = it & 31;
    float dy = ob[2 * tap], dx = ob[2 * tap + 1];
#pragma unroll
    for (int wv = 0; wv < 8; wv++) {
      dy += off_part[(wv * 32 + px) * 20 + 2 * tap];
      dx += off_part[(wv * 32 + px) * 20 + 2 * tap + 1];
    }
    int ky = tap / 3, kx = tap % 3;
    int p = p0 + px;
    int yq = p >> 6, xq = p & 63;
    float py = (float)(yq - 1 + ky) + dy;
    float pxx = (float)(xq - 1 + kx) + dx;
    float y0f = floorf(py), x0f = floorf(pxx);
    float ty = py - y0f, tx = pxx - x0f;
    int y0 = (int)y0f, x0 = (int)x0f;
    int y1 = y0 + 1, x1 = x0 + 1;
    float wy0 = 1.f - ty, wy1 = ty, wx0 = 1.f - tx, wx1 = tx;
    bool vy0 = (y0 >= 0) && (y0 < 64), vy1 = (y1 >= 0) && (y1 < 64);
    bool vx0 = (x0 >= 0) && (x0 < 64), vx1 = (x1 >= 0) && (x1 < 64);
    int cy0 = min(max(y0, 0), 63), cy1 = min(max(y1, 0), 63);
    int cx0 = min(max(x0, 0), 63), cx1 = min(max(x1, 0), 63);
    int base = b * HW;
    int4 ci;
    ci.x = (base + cy0 * 64 + cx0) * 256;
    ci.y = (base + cy0 * 64 + cx1) * 256;
    ci.z = (base + cy1 * 64 + cx0) * 256;
    ci.w = (base + cy1 * 64 + cx1) * 256;
    float4 mw;
    mw.x = wy0 * wx0 * ((vy0 && vx0) ? 1.f : 0.f);
    mw.y = wy0 * wx1 * ((vy0 && vx1) ? 1.f : 0.f);
    mw.z = wy1 * wx0 * ((vy1 && vx0) ? 1.f : 0.f);
    mw.w = wy1 * wx1 * ((vy1 && vx1) ? 1.f : 0.f);
    ci_s[it] = ci;
    mw_s[it] = mw;
  }
  __syncthreads();

  // ---- Phase B: deformable GEMM M=256, N=32; 9 tap-pairs of 2 chunks ----
  {
    int oct8 = tid & 15;   // channel octet within a 128-ch chunk
    int pxg = tid >> 4;    // pixel 0..31 (this thread's staging pixel)
    int sub = pxg >> 4;    // subtile of the staged pixel
    int pxw = pxg & 15;
    int col = lane & 15;
    int pq = lane >> 4;
    int e0 = oct8 * 8;
    f32x4_t acc[2][2] = {};  // [sub][im]

    auto stage_b = [&](uint4 c0, uint4 c1, uint4 c2, uint4 c3, float4 mw, u16* bb) {
      uint4 u;
      u.x = blend2(c0.x, c1.x, c2.x, c3.x, mw);
      u.y = blend2(c0.y, c1.y, c2.y, c3.y, mw);
      u.z = blend2(c0.z, c1.z, c2.z, c3.z, mw);
      u.w = blend2(c0.w, c1.w, c2.w, c3.w, mw);
      *(uint4*)&bb[sub * 2176 + oct8 * 136 + pxw * 8] = u;
    };
    auto gemm = [&](const u16* bb, int kcbase) {
      __builtin_amdgcn_s_setprio(1);
#pragma unroll
      for (int ks = 0; ks < 4; ks++) {
        int ro = ks * 4 + pq;
        bf16x8 bb0 = *(bf16x8*)&bb[ro * 136 + col * 8];
        bf16x8 bb1 = *(bf16x8*)&bb[2176 + ro * 136 + col * 8];
        int kc = kcbase + (ks >> 1);
        int gg = (ks & 1) * 4 + pq;
        const u16* ab = warr + kc * 16384 + gg * 2048 + (wm * 32 + col) * 8;
#pragma unroll
        for (int im = 0; im < 2; im++) {
          bf16x8 af = *(const bf16x8*)&ab[im * 128];
          acc[0][im] = __builtin_amdgcn_mfma_f32_16x16x32_bf16(af, bb0, acc[0][im], 0, 0, 0);
          acc[1][im] = __builtin_amdgcn_mfma_f32_16x16x32_bf16(af, bb1, acc[1][im], 0, 0, 0);
        }
      }
      __builtin_amdgcn_s_setprio(0);
    };

    // prologue: tap 0, both chunks (even set A = ch 0-127, odd set B = ch 128-255)
    int4 ci0 = ci_s[pxg];
    float4 mw_cur = mw_s[pxg];
    uint4 a0 = *(const uint4*)&xt[ci0.x + e0];
    uint4 a1 = *(const uint4*)&xt[ci0.y + e0];
    uint4 a2v = *(const uint4*)&xt[ci0.z + e0];
    uint4 a3 = *(const uint4*)&xt[ci0.w + e0];
    uint4 g0 = *(const uint4*)&xt[ci0.x + 128 + e0];
    uint4 g1 = *(const uint4*)&xt[ci0.y + 128 + e0];
    uint4 g2 = *(const uint4*)&xt[ci0.z + 128 + e0];
    uint4 g3 = *(const uint4*)&xt[ci0.w + 128 + e0];
    float4 mw_nxt = mw_cur;
    int4 ci_n = ci0;

#pragma unroll 1
    for (int dp = 0; dp < 9; dp++) {
      // ---- even chunk (2dp): blend set A, reload A for tap dp+1 ----
      stage_b(a0, a1, a2v, a3, mw_cur, b_s);
      __syncthreads();
      if (dp < 8) {
        ci_n = ci_s[(dp + 1) * 32 + pxg];
        mw_nxt = mw_s[(dp + 1) * 32 + pxg];
        a0 = *(const uint4*)&xt[ci_n.x + e0];
        a1 = *(const uint4*)&xt[ci_n.y + e0];
        a2v = *(const uint4*)&xt[ci_n.z + e0];
        a3 = *(const uint4*)&xt[ci_n.w + e0];
      }
      gemm(b_s, dp * 4);
      // ---- odd chunk (2dp+1): blend set B, reload B for tap dp+1 ----
      stage_b(g0, g1, g2, g3, mw_cur, b_s + 4352);
      __syncthreads();
      if (dp < 8) {
        g0 = *(const uint4*)&xt[ci_n.x + 128 + e0];
        g1 = *(const uint4*)&xt[ci_n.y + 128 + e0];
        g2 = *(const uint4*)&xt[ci_n.z + 128 + e0];
        g3 = *(const uint4*)&xt[ci_n.w + 128 + e0];
      }
      gemm(b_s + 4352, dp * 4 + 2);
      mw_cur = mw_nxt;
      // no trailing barrier: buffer re-written only after the next sync (2-deep safe)
    }

    // epilogue: D col=px-in-sub, row=pq*4+r -> NCHW; fused GN partial sums
#pragma unroll
    for (int im = 0; im < 2; im++) {
      float s = 0.f, ss = 0.f;
#pragma unroll
      for (int sb = 0; sb < 2; sb++) {
        int n = p0 + sb * 16 + col;
#pragma unroll
        for (int r = 0; r < 4; r++) {
          int m = wm * 32 + im * 16 + pq * 4 + r;
          float v = acc[sb][im][r];
          out[(b * 256 + m) * HW + n] = v;
          s += v;
          ss += v * v;
        }
      }
#pragma unroll
      for (int msk = 1; msk <= 16; msk <<= 1) {
        s += __shfl_xor(s, msk);
        ss += __shfl_xor(ss, msk);
      }
      if ((lane & 31) == 0) {
        int grp = wm * 4 + im * 2 + (lane >> 5);
        float* pp = part + (b * 32 + grp) * 2;
        atomicAdd(pp, s);
        atomicAdd(pp + 1, ss);
      }
    }
  }
}

// ---------------- Kernel N: finalize stats + normalize + ReLU in place ----------------
__global__ __launch_bounds__(256) void k_gn_apply(float* __restrict__ out,
                                                  const float2* __restrict__ part,
                                                  const float* __restrict__ gamma,
                                                  const float* __restrict__ beta) {
  int gid = blockIdx.x * 256 + threadIdx.x;  // float4 index, < 1048576
  int c = (gid >> 10) & 255;
  int bb = gid >> 18;
  float2 p = part[bb * 32 + (c >> 3)];  // broadcast load (same addr across block)
  float mu = p.x / 32768.f;
  float var = p.y / 32768.f - mu * mu;
  float rs = rsqrtf(var + 1e-5f);
  float ga = gamma[c] * rs;
  float be = beta[c] - mu * ga;
  float4 v = ((const float4*)out)[gid];
  v.x = fmaxf(v.x * ga + be, 0.f);
  v.y = fmaxf(v.y * ga + be, 0.f);
  v.z = fmaxf(v.z * ga + be, 0.f);
  v.w = fmaxf(v.w * ga + be, 0.f);
  ((float4*)out)[gid] = v;
}

extern "C" void kernel_launch(void* const* d_in, const int* in_sizes, int n_in,
                              void* d_out, int out_size, void* d_ws, size_t ws_size,
                              hipStream_t stream) {
  const float* x = (const float*)d_in[0];
  const float* offset_w = (const float*)d_in[1];
  const float* offset_b = (const float*)d_in[2];
  const float* deform_w = (const float*)d_in[3];
  const float* gn_gamma = (const float*)d_in[4];
  const float* gn_beta = (const float*)d_in[5];
  float* out = (float*)d_out;
  char* ws = (char*)d_ws;

  u16* xt = (u16*)ws;                      //  8,388,608 B (bf16 NHWC)
  u16* warr = (u16*)(ws + 8388608);        //  1,179,648 B
  u16* owm = (u16*)(ws + 9568256);         //    147,456 B
  float* part = (float*)(ws + 9715712);    //      1,024 B (4b x 32g x {s,ss})

  k_pre<<<dim3(6689), dim3(256), 0, stream>>>(x, deform_w, offset_w, xt, warr, owm, part);
  k_conv<<<dim3(512), dim3(512), 0, stream>>>(xt, warr, owm, offset_b, out, part);
  k_gn_apply<<<dim3(4096), dim3(256), 0, stream>>>(out, (const float2*)part, gn_gamma, gn_beta);
}

// Round 6
// 153.803 us; speedup vs baseline: 1.7433x; 1.0252x over previous
//
#include <hip/hip_runtime.h>
#include <hip/hip_bf16.h>
#include <stdint.h>

// DeformableBlock: fused [offset-conv (MFMA) + meta + deformable conv (MFMA GEMM)]
// -> GroupNorm+ReLU.  B=4, CIN=COUT=256, H=W=64, 3x3, GN groups=32.
// Round 15: per-tap staging. R14 post-mortem: __syncthreads' vmcnt(0) drain
// clipped the 2-set prefetch window (loads crossed the opposite set's barrier).
// Fix structurally: stage the FULL 256-ch tap -> ONE barrier -> prefetch both
// sets for tap+1 -> 8-K-step MFMA cluster. Gathers are issued post-barrier and
// consumed pre-next-barrier => no load ever crosses a barrier; drain is free.
// Barriers 18 -> 9; MFMA cluster 16 -> 32 per wave; setprio region doubled.

typedef unsigned short u16;
typedef __bf16 bf16x8 __attribute__((ext_vector_type(8)));
typedef float f32x4_t __attribute__((ext_vector_type(4)));

#define HW 4096

__device__ __forceinline__ uint32_t f32_to_bf16_rne(float f) {
  uint32_t u = __builtin_bit_cast(uint32_t, f);
  return (u + 0x7FFFu + ((u >> 16) & 1u)) >> 16;
}
__device__ __forceinline__ float bf_lo(uint32_t u) {
  return __builtin_bit_cast(float, u << 16);
}
__device__ __forceinline__ float bf_hi(uint32_t u) {
  return __builtin_bit_cast(float, u & 0xFFFF0000u);
}
__device__ __forceinline__ uint32_t blend2(uint32_t a, uint32_t b, uint32_t c,
                                           uint32_t d, float4 mw) {
  float lo = mw.x * bf_lo(a) + mw.y * bf_lo(b) + mw.z * bf_lo(c) + mw.w * bf_lo(d);
  float hi = mw.x * bf_hi(a) + mw.y * bf_hi(b) + mw.z * bf_hi(c) + mw.w * bf_hi(d);
  return f32_to_bf16_rne(lo) | (f32_to_bf16_rne(hi) << 16);
}

// ---------------- Kernel PRE: transpose + weight prep + zero part (merged) ----------------
__global__ __launch_bounds__(256) void k_pre(const float* __restrict__ x,
                                             const float* __restrict__ wsrc,
                                             const float* __restrict__ ow,
                                             u16* __restrict__ xt,
                                             u16* __restrict__ warr,
                                             u16* __restrict__ owm,
                                             float* __restrict__ part) {
  __shared__ float tile[32][33];
  int bid = blockIdx.x;
  int tid = threadIdx.x;
  if (bid < 4096) {
    int bx = bid & 127, by = (bid >> 7) & 7, bz = bid >> 10;
    int c0 = by * 32, p0 = bx * 32;
    int tx = tid & 31, ty = tid >> 5;  // 32 x 8
#pragma unroll
    for (int j = 0; j < 32; j += 8)
      tile[ty + j][tx] = x[(bz * 256 + c0 + ty + j) * HW + p0 + tx];
    __syncthreads();
    int cp = tid & 15;
    int pr = tid >> 4;
#pragma unroll
    for (int j = 0; j < 2; j++) {
      int p = pr + j * 16;
      uint32_t lo = f32_to_bf16_rne(tile[cp * 2][p]);
      uint32_t hi = f32_to_bf16_rne(tile[cp * 2 + 1][p]);
      *(uint32_t*)&xt[(bz * HW + p0 + p) * 256 + c0 + cp * 2] = lo | (hi << 16);
    }
  } else if (bid < 6400) {
    int e = (bid - 4096) * 256 + tid;  // < 589824
    int kk = e & 7, m = (e >> 3) & 255, g = (e >> 11) & 7, kc = e >> 14;
    int cin = (kc & 3) * 64 + g * 8 + kk;
    int tap = kc >> 2;
    warr[e] = (u16)f32_to_bf16_rne(wsrc[m * 2304 + cin * 9 + tap]);
  } else if (bid < 6688) {
    int e = (bid - 6400) * 256 + tid;  // < 73728
    int kk = e & 7, m = (e >> 3) & 31, g = (e >> 8) & 7, kc = e >> 11;
    int cin = (kc & 3) * 64 + g * 8 + kk;
    int tap = kc >> 2;
    float v = (m < 18) ? ow[m * 2304 + cin * 9 + tap] : 0.f;
    owm[e] = (u16)f32_to_bf16_rne(v);
  } else {
    part[tid] = 0.f;  // 4 b * 32 groups * {s,ss} = 256 floats
  }
}

// ---------------- Kernel C: FUSED offset-conv + meta + deformable GEMM + GN partials ----------------
// Block = (b, 32-px tile), 512 blocks x 512 threads (8 waves, M=32/wave).
// Phase A: offset conv M=32,N=32,K=2304 (8 waves split 36 kc-chunks, wave-private
// LDS staging, zero barriers). Meta -> LDS.
// Phase B: 9 taps; per tap: stage 256 ch (2 sets) -> 1 barrier -> prefetch both
// sets for tap+1 -> 32-MFMA cluster (setprio). No load crosses a barrier.
__global__ __launch_bounds__(512, 4) void k_conv(
    const u16* __restrict__ xt, const u16* __restrict__ warr,
    const u16* __restrict__ owm, const float* __restrict__ ob,
    float* __restrict__ out, float* __restrict__ part) {
  __shared__ char smem[54272];
  u16* stage = (u16*)smem;                   // phase A: [w8][2112 u16] (33792 B)
  float* off_part = (float*)(smem + 33792);  // phase A: [w8][px32][20]  (20480 B)
  int4* ci_s = (int4*)smem;                  // meta/B:  [288]           (4608 B)
  float4* mw_s = (float4*)(smem + 4608);     // meta/B:  [288]           (4608 B)
  u16* b_s = (u16*)(smem + 9216);            // phase B: [2buf][2set][2sub][16oct][136 u16] (34816 B)

  int tid = threadIdx.x;
  int lane = tid & 63;
  int wm = tid >> 6;  // 0..7
  // XCD-aware bijective swizzle (512 blocks, 8 XCDs): each XCD gets 64
  // consecutive work-ids (L2 working set ~2.4 MB incl. warr).
  int wk = (blockIdx.x & 7) * 64 + (blockIdx.x >> 3);
  int b = wk >> 7;
  int pt = wk & 127;
  int p0 = pt * 32;
  int yrow = p0 >> 6, xbase = p0 & 63;

  // ---- Phase A: offset conv; wave w handles kc-chunks w, w+8, w+16, ... ----
  {
    u16* st = stage + wm * 2112;
    int q = lane & 15, pq = lane >> 4;
    int oct = lane & 7, pxs = lane >> 3;  // staging map (uint4 loads)
    f32x4_t a2[2][2] = {};
#pragma unroll 1
    for (int kc = wm; kc < 36; kc += 8) {
      int tap = kc >> 2, cc = kc & 3;
      int ky = tap / 3, kx = tap % 3;
      int yy = yrow + ky - 1;
      bool vy = (yy >= 0) && (yy < 64);
#pragma unroll
      for (int i = 0; i < 4; i++) {
        int px = i * 8 + pxs;
        int xx2 = xbase + px + kx - 1;
        uint4 v = make_uint4(0u, 0u, 0u, 0u);
        if (vy && xx2 >= 0 && xx2 < 64)
          v = *(const uint4*)&xt[(b * HW + yy * 64 + xx2) * 256 + cc * 64 + oct * 8];
        *(uint4*)&st[oct * 264 + px * 8] = v;
      }
#pragma unroll
      for (int ks = 0; ks < 2; ks++) {
        int g = ks * 4 + pq;
        const u16* ab = owm + kc * 2048 + g * 256;
#pragma unroll
        for (int s = 0; s < 2; s++) {
          bf16x8 bfr = *(bf16x8*)&st[g * 264 + (s * 16 + q) * 8];
#pragma unroll
          for (int im = 0; im < 2; im++) {
            bf16x8 af = *(const bf16x8*)&ab[(im * 16 + q) * 8];
            a2[s][im] = __builtin_amdgcn_mfma_f32_16x16x32_bf16(af, bfr, a2[s][im], 0, 0, 0);
          }
        }
      }
    }
#pragma unroll
    for (int s = 0; s < 2; s++)
#pragma unroll
      for (int im = 0; im < 2; im++)
#pragma unroll
        for (int r = 0; r < 4; r++) {
          int oc = im * 16 + pq * 4 + r;
          if (oc < 18) off_part[(wm * 32 + s * 16 + q) * 20 + oc] = a2[s][im][r];
        }
  }
  __syncthreads();
  // ---- meta: 288 = 9 taps x 32 px; results to LDS (aliases dead stage) ----
  for (int it = tid; it < 288; it += 512) {
    int tap = it >> 5;
    int px = it & 31;
    float dy = ob[2 * tap], dx = ob[2 * tap + 1];
#pragma unroll
    for (int wv = 0; wv < 8; wv++) {
      dy += off_part[(wv * 32 + px) * 20 + 2 * tap];
      dx += off_part[(wv * 32 + px) * 20 + 2 * tap + 1];
    }
    int ky = tap / 3, kx = tap % 3;
    int p = p0 + px;
    int yq = p >> 6, xq = p & 63;
    float py = (float)(yq - 1 + ky) + dy;
    float pxx = (float)(xq - 1 + kx) + dx;
    float y0f = floorf(py), x0f = floorf(pxx);
    float ty = py - y0f, tx = pxx - x0f;
    int y0 = (int)y0f, x0 = (int)x0f;
    int y1 = y0 + 1, x1 = x0 + 1;
    float wy0 = 1.f - ty, wy1 = ty, wx0 = 1.f - tx, wx1 = tx;
    bool vy0 = (y0 >= 0) && (y0 < 64), vy1 = (y1 >= 0) && (y1 < 64);
    bool vx0 = (x0 >= 0) && (x0 < 64), vx1 = (x1 >= 0) && (x1 < 64);
    int cy0 = min(max(y0, 0), 63), cy1 = min(max(y1, 0), 63);
    int cx0 = min(max(x0, 0), 63), cx1 = min(max(x1, 0), 63);
    int base = b * HW;
    int4 ci;
    ci.x = (base + cy0 * 64 + cx0) * 256;
    ci.y = (base + cy0 * 64 + cx1) * 256;
    ci.z = (base + cy1 * 64 + cx0) * 256;
    ci.w = (base + cy1 * 64 + cx1) * 256;
    float4 mw;
    mw.x = wy0 * wx0 * ((vy0 && vx0) ? 1.f : 0.f);
    mw.y = wy0 * wx1 * ((vy0 && vx1) ? 1.f : 0.f);
    mw.z = wy1 * wx0 * ((vy1 && vx0) ? 1.f : 0.f);
    mw.w = wy1 * wx1 * ((vy1 && vx1) ? 1.f : 0.f);
    ci_s[it] = ci;
    mw_s[it] = mw;
  }
  __syncthreads();

  // ---- Phase B: deformable GEMM M=256, N=32; 9 taps, 1 barrier/tap ----
  {
    int oct8 = tid & 15;   // channel octet within a 128-ch set
    int pxg = tid >> 4;    // pixel 0..31 (this thread's staging pixel)
    int sub = pxg >> 4;    // subtile of the staged pixel
    int pxw = pxg & 15;
    int col = lane & 15;
    int pq = lane >> 4;
    int e0 = oct8 * 8;
    f32x4_t acc[2][2] = {};  // [sub][im]

    // prologue: gather tap 0, both 128-ch sets
    int4 ci = ci_s[pxg];
    float4 mw = mw_s[pxg];
    uint4 A0 = *(const uint4*)&xt[ci.x + e0];
    uint4 A1 = *(const uint4*)&xt[ci.y + e0];
    uint4 A2 = *(const uint4*)&xt[ci.z + e0];
    uint4 A3 = *(const uint4*)&xt[ci.w + e0];
    uint4 G0 = *(const uint4*)&xt[ci.x + 128 + e0];
    uint4 G1 = *(const uint4*)&xt[ci.y + 128 + e0];
    uint4 G2 = *(const uint4*)&xt[ci.z + 128 + e0];
    uint4 G3 = *(const uint4*)&xt[ci.w + 128 + e0];

#pragma unroll 1
    for (int dp = 0; dp < 9; dp++) {
      u16* bb = b_s + (dp & 1) * 8704;
      // stage full tap: set 0 (ch 0-127) + set 1 (ch 128-255)
      {
        uint4 u;
        u.x = blend2(A0.x, A1.x, A2.x, A3.x, mw);
        u.y = blend2(A0.y, A1.y, A2.y, A3.y, mw);
        u.z = blend2(A0.z, A1.z, A2.z, A3.z, mw);
        u.w = blend2(A0.w, A1.w, A2.w, A3.w, mw);
        *(uint4*)&bb[sub * 2176 + oct8 * 136 + pxw * 8] = u;
      }
      {
        uint4 v;
        v.x = blend2(G0.x, G1.x, G2.x, G3.x, mw);
        v.y = blend2(G0.y, G1.y, G2.y, G3.y, mw);
        v.z = blend2(G0.z, G1.z, G2.z, G3.z, mw);
        v.w = blend2(G0.w, G1.w, G2.w, G3.w, mw);
        *(uint4*)&bb[4352 + sub * 2176 + oct8 * 136 + pxw * 8] = v;
      }
      __syncthreads();  // all gathers already consumed -> vmcnt drain is free
      // prefetch tap dp+1 (issued here, consumed before the NEXT barrier:
      // these loads never cross a barrier)
      if (dp < 8) {
        ci = ci_s[(dp + 1) * 32 + pxg];
        float4 mwn = mw_s[(dp + 1) * 32 + pxg];
        A0 = *(const uint4*)&xt[ci.x + e0];
        A1 = *(const uint4*)&xt[ci.y + e0];
        A2 = *(const uint4*)&xt[ci.z + e0];
        A3 = *(const uint4*)&xt[ci.w + e0];
        G0 = *(const uint4*)&xt[ci.x + 128 + e0];
        G1 = *(const uint4*)&xt[ci.y + 128 + e0];
        G2 = *(const uint4*)&xt[ci.z + 128 + e0];
        G3 = *(const uint4*)&xt[ci.w + 128 + e0];
        mw = mwn;
      }
      // GEMM over the full tap: 8 K-steps, 32 MFMA per wave
      __builtin_amdgcn_s_setprio(1);
#pragma unroll
      for (int ks = 0; ks < 8; ks++) {
        int set = ks >> 2;
        int ro = (ks & 3) * 4 + pq;
        const u16* bp = bb + set * 4352 + ro * 136 + col * 8;
        bf16x8 bb0 = *(const bf16x8*)&bp[0];
        bf16x8 bb1 = *(const bf16x8*)&bp[2176];
        int kc = dp * 4 + (ks >> 1);
        int gg = (ks & 1) * 4 + pq;
        const u16* ab = warr + kc * 16384 + gg * 2048 + (wm * 32 + col) * 8;
#pragma unroll
        for (int im = 0; im < 2; im++) {
          bf16x8 af = *(const bf16x8*)&ab[im * 128];
          acc[0][im] = __builtin_amdgcn_mfma_f32_16x16x32_bf16(af, bb0, acc[0][im], 0, 0, 0);
          acc[1][im] = __builtin_amdgcn_mfma_f32_16x16x32_bf16(af, bb1, acc[1][im], 0, 0, 0);
        }
      }
      __builtin_amdgcn_s_setprio(0);
      // no trailing barrier: next dp writes the other buffer (2-deep rotation safe)
    }

    // epilogue: D col=px-in-sub, row=pq*4+r -> NCHW; fused GN partial sums
#pragma unroll
    for (int im = 0; im < 2; im++) {
      float s = 0.f, ss = 0.f;
#pragma unroll
      for (int sb = 0; sb < 2; sb++) {
        int n = p0 + sb * 16 + col;
#pragma unroll
        for (int r = 0; r < 4; r++) {
          int m = wm * 32 + im * 16 + pq * 4 + r;
          float v = acc[sb][im][r];
          out[(b * 256 + m) * HW + n] = v;
          s += v;
          ss += v * v;
        }
      }
#pragma unroll
      for (int msk = 1; msk <= 16; msk <<= 1) {
        s += __shfl_xor(s, msk);
        ss += __shfl_xor(ss, msk);
      }
      if ((lane & 31) == 0) {
        int grp = wm * 4 + im * 2 + (lane >> 5);
        float* pp = part + (b * 32 + grp) * 2;
        atomicAdd(pp, s);
        atomicAdd(pp + 1, ss);
      }
    }
  }
}

// ---------------- Kernel N: finalize stats + normalize + ReLU in place ----------------
__global__ __launch_bounds__(256) void k_gn_apply(float* __restrict__ out,
                                                  const float2* __restrict__ part,
                                                  const float* __restrict__ gamma,
                                                  const float* __restrict__ beta) {
  int gid = blockIdx.x * 256 + threadIdx.x;  // float4 index, < 1048576
  int c = (gid >> 10) & 255;
  int bb = gid >> 18;
  float2 p = part[bb * 32 + (c >> 3)];  // broadcast load (same addr across block)
  float mu = p.x / 32768.f;
  float var = p.y / 32768.f - mu * mu;
  float rs = rsqrtf(var + 1e-5f);
  float ga = gamma[c] * rs;
  float be = beta[c] - mu * ga;
  float4 v = ((const float4*)out)[gid];
  v.x = fmaxf(v.x * ga + be, 0.f);
  v.y = fmaxf(v.y * ga + be, 0.f);
  v.z = fmaxf(v.z * ga + be, 0.f);
  v.w = fmaxf(v.w * ga + be, 0.f);
  ((float4*)out)[gid] = v;
}

extern "C" void kernel_launch(void* const* d_in, const int* in_sizes, int n_in,
                              void* d_out, int out_size, void* d_ws, size_t ws_size,
                              hipStream_t stream) {
  const float* x = (const float*)d_in[0];
  const float* offset_w = (const float*)d_in[1];
  const float* offset_b = (const float*)d_in[2];
  const float* deform_w = (const float*)d_in[3];
  const float* gn_gamma = (const float*)d_in[4];
  const float* gn_beta = (const float*)d_in[5];
  float* out = (float*)d_out;
  char* ws = (char*)d_ws;

  u16* xt = (u16*)ws;                      //  8,388,608 B (bf16 NHWC)
  u16* warr = (u16*)(ws + 8388608);        //  1,179,648 B
  u16* owm = (u16*)(ws + 9568256);         //    147,456 B
  float* part = (float*)(ws + 9715712);    //      1,024 B (4b x 32g x {s,ss})

  k_pre<<<dim3(6689), dim3(256), 0, stream>>>(x, deform_w, offset_w, xt, warr, owm, part);
  k_conv<<<dim3(512), dim3(512), 0, stream>>>(xt, warr, owm, offset_b, out, part);
  k_gn_apply<<<dim3(4096), dim3(256), 0, stream>>>(out, (const float2*)part, gn_gamma, gn_beta);
}